// Round 4
// baseline (52.641 us; speedup 1.0000x reference)
//
#include <hip/hip_runtime.h>
#include <hip/hip_bf16.h>
#include <stdint.h>

// Problem constants (from reference)
#define N_SAMP 16384
#define DCONT  64
#define DCAT   2000
#define EMB    64
#define K_CAT_PAD 2048          // 64 K-steps of 32 (k 2000..2047 zero-padded in B)
#define K_PAD     2112          // + 64 continuous K at the end

typedef short bf16x8 __attribute__((ext_vector_type(8)));
typedef float f32x4  __attribute__((ext_vector_type(4)));

__device__ __forceinline__ uint16_t f2bf(float f) {
    union { float f; uint32_t u; } v; v.f = f;
    uint32_t r = v.u + 0x7FFFu + ((v.u >> 16) & 1u);   // RNE
    return (uint16_t)(r >> 16);
}
__device__ __forceinline__ uint32_t pack2f(float a, float b) {
    return (uint32_t)f2bf(a) | ((uint32_t)f2bf(b) << 16);
}

// Build B_T[c][k] (bf16), c in [0,64), k in [0,2112):
//   k <  2000          : W_cat[k][c]
//   2000 <= k < 2048   : 0   (pad so the cat phase is 64 aligned K=32 steps)
//   2048 <= k < 2112   : W_cont[k-2048][c]
__global__ void build_b_kernel(const float* __restrict__ Wcont,
                               const float* __restrict__ Wcat,
                               uint16_t* __restrict__ Bws) {
    int k = blockIdx.x * 64 + threadIdx.x;   // coalesced along k
    int c = blockIdx.y;
    float v = 0.f;
    if (k < DCAT)            v = Wcat[(long)k * EMB + c];
    else if (k >= K_CAT_PAD) v = Wcont[(long)(k - K_CAT_PAD) * EMB + c];
    Bws[(long)c * K_PAD + k] = f2bf(v);
}

struct AFrag { int4 a0, a1; };
struct BFrag { bf16x8 b0, b1, b2, b3; };

__global__ __launch_bounds__(256, 4)
void fm_kernel(const float* __restrict__ xc,
               const int*   __restrict__ xcat,
               const uint16_t* __restrict__ Bws,
               float* __restrict__ out) {
    // 4 waves per block; each wave computes a PARTIAL s for the same 16 rows
    // over a quarter of K (no barriers in the main loop). Epilogue combines.
    // Pipeline: A prefetched 4 steps ahead (HBM ~900cy), B 2 ahead (L2 ~200cy).
    __shared__ float part[4][16][EMB];

    const int tid  = threadIdx.x;
    const int w    = tid >> 6;
    const int lane = tid & 63;
    const int g    = lane >> 4;        // k-chunk within fragment (8 elems)
    const int lr   = lane & 15;        // row (A) / col (B) within tile
    const int r0   = blockIdx.x * 16;

    f32x4 acc[4] = { {0,0,0,0}, {0,0,0,0}, {0,0,0,0}, {0,0,0,0} };

    const long aBase = (long)(r0 + lr) * DCAT;   // xcat row base (ints)
    const int  kw    = w * 512;                  // this wave's cat k-range start

    auto loadA = [&](int kbase) -> AFrag {
        AFrag f;
        const int kg = kbase + g * 8;
        if (kg + 8 <= DCAT) {
            f.a0 = *(const int4*)(xcat + aBase + kg);
            f.a1 = *(const int4*)(xcat + aBase + kg + 4);
        } else {
            f.a0 = make_int4(0, 0, 0, 0);
            f.a1 = make_int4(0, 0, 0, 0);
        }
        return f;
    };
    auto loadB = [&](int kbase) -> BFrag {
        BFrag f;
        const int kg = kbase + g * 8;
        f.b0 = *(const bf16x8*)(Bws + (long)(0 * 16 + lr) * K_PAD + kg);
        f.b1 = *(const bf16x8*)(Bws + (long)(1 * 16 + lr) * K_PAD + kg);
        f.b2 = *(const bf16x8*)(Bws + (long)(2 * 16 + lr) * K_PAD + kg);
        f.b3 = *(const bf16x8*)(Bws + (long)(3 * 16 + lr) * K_PAD + kg);
        return f;
    };
    // mask int {0,1} -> bf16 {0.0, 1.0}: (a + (b<<16)) * 0x3F80, 24-bit safe
    auto catFrag = [&](const AFrag& A) -> bf16x8 {
        union { uint32_t u[4]; bf16x8 v; } cv;
        cv.u[0] = (uint32_t)((A.a0.x + (A.a0.y << 16)) * 0x3F80u);
        cv.u[1] = (uint32_t)((A.a0.z + (A.a0.w << 16)) * 0x3F80u);
        cv.u[2] = (uint32_t)((A.a1.x + (A.a1.y << 16)) * 0x3F80u);
        cv.u[3] = (uint32_t)((A.a1.z + (A.a1.w << 16)) * 0x3F80u);
        return cv.v;
    };
    auto mmac = [&](bf16x8 af, const BFrag& B) {
        acc[0] = __builtin_amdgcn_mfma_f32_16x16x32_bf16(af, B.b0, acc[0], 0, 0, 0);
        acc[1] = __builtin_amdgcn_mfma_f32_16x16x32_bf16(af, B.b1, acc[1], 0, 0, 0);
        acc[2] = __builtin_amdgcn_mfma_f32_16x16x32_bf16(af, B.b2, acc[2], 0, 0, 0);
        acc[3] = __builtin_amdgcn_mfma_f32_16x16x32_bf16(af, B.b3, acc[3], 0, 0, 0);
    };

    // --- cat main loop: 16 K-steps of 32, rotating register pipeline, no barriers
    AFrag ab[4]; BFrag bb[2];
    ab[0] = loadA(kw);
    ab[1] = loadA(kw + 32);
    ab[2] = loadA(kw + 64);
    ab[3] = loadA(kw + 96);
    bb[0] = loadB(kw);
    bb[1] = loadB(kw + 32);
    #pragma unroll
    for (int s = 0; s < 16; ++s) {
        bf16x8 af = catFrag(ab[s & 3]);
        if (s + 4 < 16) ab[s & 3] = loadA(kw + (s + 4) * 32);
        BFrag bc = bb[s & 1];
        if (s + 2 < 16) bb[s & 1] = loadB(kw + (s + 2) * 32);
        mmac(af, bc);
    }

    // --- continuous part: waves 2 and 3 take one 32-wide K-step each
    if (w >= 2) {
        const int cs = w - 2;                       // 0 or 1
        const long cBase = (long)(r0 + lr) * DCONT + cs * 32 + g * 8;
        float4 x0 = *(const float4*)(xc + cBase);
        float4 x1 = *(const float4*)(xc + cBase + 4);
        BFrag bcc = loadB(K_CAT_PAD + cs * 32);
        union { uint32_t u[4]; bf16x8 v; } cv;
        cv.u[0] = pack2f(x0.x, x0.y);
        cv.u[1] = pack2f(x0.z, x0.w);
        cv.u[2] = pack2f(x1.x, x1.y);
        cv.u[3] = pack2f(x1.z, x1.w);
        mmac(cv.v, bcc);
    }

    // --- epilogue: combine 4 wave-partials, out[r] = 0.5 * ||s_row||^2
    // lane (g,lr) holds rows g*4+r, col n*16+lr
    #pragma unroll
    for (int n = 0; n < 4; ++n) {
        #pragma unroll
        for (int r = 0; r < 4; ++r)
            part[w][g * 4 + r][n * 16 + lr] = acc[n][r];
    }
    __syncthreads();

    const int row = tid >> 4;            // 0..15
    const int c0  = (tid & 15) * 4;      // 4 cols per thread
    float4 v0 = *(const float4*)&part[0][row][c0];
    float4 v1 = *(const float4*)&part[1][row][c0];
    float4 v2 = *(const float4*)&part[2][row][c0];
    float4 v3 = *(const float4*)&part[3][row][c0];
    float sx = v0.x + v1.x + v2.x + v3.x;
    float sy = v0.y + v1.y + v2.y + v3.y;
    float sz = v0.z + v1.z + v2.z + v3.z;
    float sw_ = v0.w + v1.w + v2.w + v3.w;
    float p = sx * sx + sy * sy + sz * sz + sw_ * sw_;
    p += __shfl_xor(p, 1);
    p += __shfl_xor(p, 2);
    p += __shfl_xor(p, 4);
    p += __shfl_xor(p, 8);
    if ((tid & 15) == 0) out[r0 + row] = 0.5f * p;
}

extern "C" void kernel_launch(void* const* d_in, const int* in_sizes, int n_in,
                              void* d_out, int out_size, void* d_ws, size_t ws_size,
                              hipStream_t stream) {
    const float* xc    = (const float*)d_in[0];   // data_continuous [N,64] f32
    const int*   xcat  = (const int*)d_in[1];     // data_category   [N,2000] i32
    const float* Wcont = (const float*)d_in[2];   // [64,64] f32
    const float* Wcat  = (const float*)d_in[3];   // [2000,64] f32
    uint16_t* Bws = (uint16_t*)d_ws;              // B_T[64][2112] bf16 = 264 KiB
    float* outp = (float*)d_out;

    build_b_kernel<<<dim3(K_PAD / 64, EMB), 64, 0, stream>>>(Wcont, Wcat, Bws);
    fm_kernel<<<N_SAMP / 16, 256, 0, stream>>>(xc, xcat, Bws, outp);
}

// Round 5
// 42.121 us; speedup vs baseline: 1.2498x; 1.2498x over previous
//
#include <hip/hip_runtime.h>
#include <hip/hip_bf16.h>
#include <stdint.h>

// Problem constants (from reference)
#define N_SAMP 16384
#define DCONT  64
#define DCAT   2000
#define EMB    64
#define K_CAT_PAD 2048          // 64 K-steps of 32 (k 2000..2047 zero-masked)
#define K_PAD     2112          // + 64 continuous K at the end
#define BM 32                   // rows per block (= rows per wave)
#define TAIL_OFF 270336         // bytes into d_ws for padded last xcat row (64*2112*2)

typedef short bf16x8 __attribute__((ext_vector_type(8)));
typedef float f32x4  __attribute__((ext_vector_type(4)));

__device__ __forceinline__ uint16_t f2bf(float f) {
    union { float f; uint32_t u; } v; v.f = f;
    uint32_t r = v.u + 0x7FFFu + ((v.u >> 16) & 1u);   // RNE
    return (uint16_t)(r >> 16);
}
__device__ __forceinline__ uint32_t pack2f(float a, float b) {
    return (uint32_t)f2bf(a) | ((uint32_t)f2bf(b) << 16);
}

// Build B_T[c][k] (bf16), c in [0,64), k in [0,2112):
//   k <  2000          : W_cat[k][c]
//   2000 <= k < 2048   : 0
//   2048 <= k < 2112   : W_cont[k-2048][c]
__global__ void build_b_kernel(const float* __restrict__ Wcont,
                               const float* __restrict__ Wcat,
                               uint16_t* __restrict__ Bws) {
    int k = blockIdx.x * 64 + threadIdx.x;   // coalesced along k
    int c = blockIdx.y;
    float v = 0.f;
    if (k < DCAT)            v = Wcat[(long)k * EMB + c];
    else if (k >= K_CAT_PAD) v = Wcont[(long)(k - K_CAT_PAD) * EMB + c];
    Bws[(long)c * K_PAD + k] = f2bf(v);
}

// Zero-padded copy of the LAST xcat row so fm_kernel never reads past the buffer.
__global__ void build_tail_kernel(const int* __restrict__ xcat,
                                  int* __restrict__ tailA) {
    int k = blockIdx.x * 256 + threadIdx.x;   // 0..2047
    tailA[k] = (k < DCAT) ? xcat[(long)(N_SAMP - 1) * DCAT + k] : 0;
}

struct A2 { int4 a0, a1, a2, a3; };            // 2 row-frags x 8 k-ints
struct BFrag { bf16x8 b0, b1, b2, b3; };       // 4 col-frags

__global__ __launch_bounds__(256, 4)
void fm_kernel(const float* __restrict__ xc,
               const int*   __restrict__ xcat,
               const uint16_t* __restrict__ Bws,
               const int*   __restrict__ tailA,
               float* __restrict__ out) {
    // 4 waves/block; each wave: SAME 32 rows, its own K-quarter (512 cat k).
    // No barriers in main loop; depth-2 register pipeline pinned by sched_barrier.
    __shared__ float part[4][BM][EMB];         // 32 KiB

    const int tid  = threadIdx.x;
    const int w    = tid >> 6;
    const int lane = tid & 63;
    const int g    = lane >> 4;
    const int lr   = lane & 15;
    const int r0   = blockIdx.x * BM;

    f32x4 acc[2][4] = { { {0,0,0,0},{0,0,0,0},{0,0,0,0},{0,0,0,0} },
                        { {0,0,0,0},{0,0,0,0},{0,0,0,0},{0,0,0,0} } };

    const int kw   = w * 512;
    const int row1 = r0 + 16 + lr;
    const int* aP0 = xcat + (long)(r0 + lr) * DCAT;
    const int* aP1 = (row1 == N_SAMP - 1) ? tailA : (xcat + (long)row1 * DCAT);
    const uint16_t* bP = Bws + (long)lr * K_PAD;

    auto loadA = [&](int s) -> A2 {
        A2 f;
        const int kg = kw + s * 32 + g * 8;
        f.a0 = *(const int4*)(aP0 + kg);
        f.a1 = *(const int4*)(aP0 + kg + 4);
        f.a2 = *(const int4*)(aP1 + kg);
        f.a3 = *(const int4*)(aP1 + kg + 4);
        return f;
    };
    auto loadB = [&](int kbase) -> BFrag {
        BFrag f;
        const int kg = kbase + g * 8;
        f.b0 = *(const bf16x8*)(bP + 0 * 16 * K_PAD + kg);
        f.b1 = *(const bf16x8*)(bP + 1 * 16 * K_PAD + kg);
        f.b2 = *(const bf16x8*)(bP + 2 * 16 * K_PAD + kg);
        f.b3 = *(const bf16x8*)(bP + 3 * 16 * K_PAD + kg);
        return f;
    };
    // mask ints {0,1} -> bf16 {0,1}*valid: (a + (b<<16)) * m, m = 0x3F80 or 0
    auto cvt = [&](const int4& x, const int4& y, uint32_t m) -> bf16x8 {
        union { uint32_t u[4]; bf16x8 v; } cv;
        cv.u[0] = (uint32_t)(x.x + (x.y << 16)) * m;
        cv.u[1] = (uint32_t)(x.z + (x.w << 16)) * m;
        cv.u[2] = (uint32_t)(y.x + (y.y << 16)) * m;
        cv.u[3] = (uint32_t)(y.z + (y.w << 16)) * m;
        return cv.v;
    };
    auto mmac = [&](bf16x8 af0, bf16x8 af1, const BFrag& B) {
        acc[0][0] = __builtin_amdgcn_mfma_f32_16x16x32_bf16(af0, B.b0, acc[0][0], 0, 0, 0);
        acc[0][1] = __builtin_amdgcn_mfma_f32_16x16x32_bf16(af0, B.b1, acc[0][1], 0, 0, 0);
        acc[0][2] = __builtin_amdgcn_mfma_f32_16x16x32_bf16(af0, B.b2, acc[0][2], 0, 0, 0);
        acc[0][3] = __builtin_amdgcn_mfma_f32_16x16x32_bf16(af0, B.b3, acc[0][3], 0, 0, 0);
        acc[1][0] = __builtin_amdgcn_mfma_f32_16x16x32_bf16(af1, B.b0, acc[1][0], 0, 0, 0);
        acc[1][1] = __builtin_amdgcn_mfma_f32_16x16x32_bf16(af1, B.b1, acc[1][1], 0, 0, 0);
        acc[1][2] = __builtin_amdgcn_mfma_f32_16x16x32_bf16(af1, B.b2, acc[1][2], 0, 0, 0);
        acc[1][3] = __builtin_amdgcn_mfma_f32_16x16x32_bf16(af1, B.b3, acc[1][3], 0, 0, 0);
    };

    // --- prologue: 2-deep
    A2 ab0 = loadA(0), ab1 = loadA(1);
    BFrag bb0 = loadB(kw), bb1 = loadB(kw + 32);

    #pragma unroll
    for (int s = 0; s < 16; ++s) {
        const uint32_t m = ((kw + s * 32 + g * 8) < DCAT) ? 0x3F80u : 0u;
        A2&    abC = (s & 1) ? ab1 : ab0;
        BFrag& bbC = (s & 1) ? bb1 : bb0;
        bf16x8 af0 = cvt(abC.a0, abC.a1, m);
        bf16x8 af1 = cvt(abC.a2, abC.a3, m);
        if (s + 2 < 16) abC = loadA(s + 2);          // issue 2 steps ahead
        __builtin_amdgcn_sched_barrier(0);            // pin: loads issued above
        mmac(af0, af1, bbC);
        if (s + 2 < 16) bbC = loadB(kw + (s + 2) * 32);
        __builtin_amdgcn_sched_barrier(0);
    }

    // --- continuous part: waves 2,3 take one 32-wide K-step each
    if (w >= 2) {
        const int cs = w - 2;
        const float* xP0 = xc + (long)(r0 + lr) * DCONT + cs * 32 + g * 8;
        const float* xP1 = xc + (long)(r0 + 16 + lr) * DCONT + cs * 32 + g * 8;
        float4 x0 = *(const float4*)(xP0);
        float4 x1 = *(const float4*)(xP0 + 4);
        float4 x2 = *(const float4*)(xP1);
        float4 x3 = *(const float4*)(xP1 + 4);
        BFrag bc = loadB(K_CAT_PAD + cs * 32);
        union { uint32_t u[4]; bf16x8 v; } c0, c1;
        c0.u[0] = pack2f(x0.x, x0.y); c0.u[1] = pack2f(x0.z, x0.w);
        c0.u[2] = pack2f(x1.x, x1.y); c0.u[3] = pack2f(x1.z, x1.w);
        c1.u[0] = pack2f(x2.x, x2.y); c1.u[1] = pack2f(x2.z, x2.w);
        c1.u[2] = pack2f(x3.x, x3.y); c1.u[3] = pack2f(x3.z, x3.w);
        mmac(c0.v, c1.v, bc);
    }

    // --- epilogue: combine 4 wave-partials; out[r] = 0.5*||s_row||^2
    // lane (g,lr): rows rf*16 + g*4 + r, col n*16 + lr
    #pragma unroll
    for (int rf = 0; rf < 2; ++rf)
        #pragma unroll
        for (int n = 0; n < 4; ++n)
            #pragma unroll
            for (int r = 0; r < 4; ++r)
                part[w][rf * 16 + g * 4 + r][n * 16 + lr] = acc[rf][n][r];
    __syncthreads();

    const int row = tid >> 3;           // 0..31
    const int c0i = (tid & 7) * 8;      // 8 cols per thread
    float p = 0.f;
    #pragma unroll
    for (int h = 0; h < 2; ++h) {
        float4 v0 = *(const float4*)&part[0][row][c0i + h * 4];
        float4 v1 = *(const float4*)&part[1][row][c0i + h * 4];
        float4 v2 = *(const float4*)&part[2][row][c0i + h * 4];
        float4 v3 = *(const float4*)&part[3][row][c0i + h * 4];
        float sx = v0.x + v1.x + v2.x + v3.x;
        float sy = v0.y + v1.y + v2.y + v3.y;
        float sz = v0.z + v1.z + v2.z + v3.z;
        float sw_ = v0.w + v1.w + v2.w + v3.w;
        p += sx * sx + sy * sy + sz * sz + sw_ * sw_;
    }
    p += __shfl_xor(p, 1);
    p += __shfl_xor(p, 2);
    p += __shfl_xor(p, 4);
    if ((tid & 7) == 0) out[r0 + row] = 0.5f * p;
}

extern "C" void kernel_launch(void* const* d_in, const int* in_sizes, int n_in,
                              void* d_out, int out_size, void* d_ws, size_t ws_size,
                              hipStream_t stream) {
    const float* xc    = (const float*)d_in[0];   // data_continuous [N,64] f32
    const int*   xcat  = (const int*)d_in[1];     // data_category   [N,2000] i32
    const float* Wcont = (const float*)d_in[2];   // [64,64] f32
    const float* Wcat  = (const float*)d_in[3];   // [2000,64] f32
    uint16_t* Bws  = (uint16_t*)d_ws;             // B_T[64][2112] bf16
    int*      tailA = (int*)((char*)d_ws + TAIL_OFF);
    float* outp = (float*)d_out;

    build_b_kernel<<<dim3(K_PAD / 64, EMB), 64, 0, stream>>>(Wcont, Wcat, Bws);
    build_tail_kernel<<<8, 256, 0, stream>>>(xcat, tailA);
    fm_kernel<<<N_SAMP / BM, 256, 0, stream>>>(xc, xcat, Bws, tailA, outp);
}